// Round 2
// baseline (88.054 us; speedup 1.0000x reference)
//
#include <hip/hip_runtime.h>
#include <hip/hip_cooperative_groups.h>
#include <math.h>

namespace cg = cooperative_groups;

#define NCLS 3
#define NYAW 2
#define NYG 160
#define NXG 160
#define NB 32
#define NANCH (NYAW * NYG * NXG)   /* 51200 */
#define DOF 7
#define EPSI 1e-8f
#define NTHREADS 256
#define NBLOCKS (NANCH / NTHREADS) /* 200 */

/* output layout (floats) */
#define OFF_GCLS 0
#define OFF_GREG (NCLS * NANCH)                    /* 153600 */
#define OFF_MCLS (OFF_GREG + NCLS * NANCH * DOF)   /* 1228800 */
#define OFF_MREG (OFF_MCLS + NANCH)                /* 1280000 */

struct BBev { float x, y, w, l, yaw; };

__device__ __forceinline__ float crossv(float ax, float ay, float bx, float by) {
    return ax * by - ay * bx;
}

/* Rotated-box IoU, mirroring the reference _pair_iou step by step.
   b1 = ground-truth box (corners first in the point list), b2 = anchor. */
__device__ float pair_iou(const BBev b1, const BBev b2) {
    /* quick reject: if bounding circles don't overlap, every mask in the
       reference is false -> inter = 0 -> iou = exactly 0.0 */
    float ddx = b1.x - b2.x, ddy = b1.y - b2.y;
    float r1 = 0.5f * sqrtf(b1.w * b1.w + b1.l * b1.l);
    float r2 = 0.5f * sqrtf(b2.w * b2.w + b2.l * b2.l);
    float rr = r1 + r2 + 1e-3f;  /* margin covers the 1e-5 inside tolerance */
    if (ddx * ddx + ddy * ddy > rr * rr) return 0.0f;

    float cs1 = cosf(b1.yaw), sn1 = sinf(b1.yaw);
    float cs2 = cosf(b2.yaw), sn2 = sinf(b2.yaw);

    float c1x[4], c1y[4], c2x[4], c2y[4];
    {
        float ux = cs1 * (b1.w * 0.5f), uy = sn1 * (b1.w * 0.5f);
        float vx = -sn1 * (b1.l * 0.5f), vy = cs1 * (b1.l * 0.5f);
        c1x[0] = b1.x + ux + vx; c1y[0] = b1.y + uy + vy;
        c1x[1] = b1.x + ux - vx; c1y[1] = b1.y + uy - vy;
        c1x[2] = b1.x - ux - vx; c1y[2] = b1.y - uy - vy;
        c1x[3] = b1.x - ux + vx; c1y[3] = b1.y - uy + vy;
    }
    {
        float ux = cs2 * (b2.w * 0.5f), uy = sn2 * (b2.w * 0.5f);
        float vx = -sn2 * (b2.l * 0.5f), vy = cs2 * (b2.l * 0.5f);
        c2x[0] = b2.x + ux + vx; c2y[0] = b2.y + uy + vy;
        c2x[1] = b2.x + ux - vx; c2y[1] = b2.y + uy - vy;
        c2x[2] = b2.x - ux - vx; c2y[2] = b2.y - uy - vy;
        c2x[3] = b2.x - ux + vx; c2y[3] = b2.y - uy + vy;
    }

    /* collect valid points in reference concat order: c1, c2, ipts(i-major) */
    float qx[24], qy[24];
    int n = 0;

    for (int i = 0; i < 4; i++) {  /* c1 corners inside b2 */
        float rx = c1x[i] - b2.x, ry = c1y[i] - b2.y;
        float du = rx * cs2 + ry * sn2;
        float dv = -rx * sn2 + ry * cs2;
        if (fabsf(du) <= b2.w * 0.5f + 1e-5f && fabsf(dv) <= b2.l * 0.5f + 1e-5f) {
            qx[n] = c1x[i]; qy[n] = c1y[i]; n++;
        }
    }
    for (int i = 0; i < 4; i++) {  /* c2 corners inside b1 */
        float rx = c2x[i] - b1.x, ry = c2y[i] - b1.y;
        float du = rx * cs1 + ry * sn1;
        float dv = -rx * sn1 + ry * cs1;
        if (fabsf(du) <= b1.w * 0.5f + 1e-5f && fabsf(dv) <= b1.l * 0.5f + 1e-5f) {
            qx[n] = c2x[i]; qy[n] = c2y[i]; n++;
        }
    }
    for (int i = 0; i < 4; i++) {  /* edge-edge intersections */
        float d1x = c1x[(i + 1) & 3] - c1x[i];
        float d1y = c1y[(i + 1) & 3] - c1y[i];
        for (int j = 0; j < 4; j++) {
            float d2x = c2x[(j + 1) & 3] - c2x[j];
            float d2y = c2y[(j + 1) & 3] - c2y[j];
            float den = crossv(d1x, d1y, d2x, d2y);
            if (fabsf(den) < EPSI) continue;
            float qpx = c2x[j] - c1x[i], qpy = c2y[j] - c1y[i];
            float t = crossv(qpx, qpy, d2x, d2y) / den;
            float s = crossv(qpx, qpy, d1x, d1y) / den;
            if (t >= 0.0f && t <= 1.0f && s >= 0.0f && s <= 1.0f) {
                qx[n] = c1x[i] + t * d1x;
                qy[n] = c1y[i] + t * d1y;
                n++;
            }
        }
    }

    float inter = 0.0f;
    if (n > 0) {
        float sx = 0.0f, sy = 0.0f;
        for (int k = 0; k < n; k++) { sx += qx[k]; sy += qy[k]; }
        float cx = sx / (float)n, cy = sy / (float)n;

        float ang[24];
        for (int k = 0; k < n; k++) ang[k] = atan2f(qy[k] - cy, qx[k] - cx);

        /* stable insertion sort by angle (matches stable argsort) */
        for (int k = 1; k < n; k++) {
            float aa = ang[k], x = qx[k], y = qy[k];
            int m = k - 1;
            while (m >= 0 && ang[m] > aa) {
                ang[m + 1] = ang[m]; qx[m + 1] = qx[m]; qy[m + 1] = qy[m];
                m--;
            }
            ang[m + 1] = aa; qx[m + 1] = x; qy[m + 1] = y;
        }

        float area = 0.0f;
        for (int k = 0; k < n; k++) {
            int kn = (k + 1 == n) ? 0 : k + 1;
            area += qx[k] * qy[kn] - qx[kn] * qy[k];
        }
        inter = 0.5f * fabsf(area);
    }

    float uni = b1.w * b1.l + b2.w * b2.l - inter;
    float iou = inter / fmaxf(uni, EPSI);
    return fminf(fmaxf(iou, 0.0f), 1.0f);
}

__global__ void __launch_bounds__(NTHREADS)
fused_kernel(const float* __restrict__ boxes,
             const float* __restrict__ anchors,
             const int* __restrict__ cls,
             float* __restrict__ out,
             float* __restrict__ highest) {
    __shared__ float sbx[NB], sby[NB], sbw[NB], sbl[NB], sbyaw[NB];
    __shared__ int scls[NB];
    __shared__ float shigh[NB];
    __shared__ float siou[NTHREADS][NB + 1];  /* +1 pad: conflict-free runtime-b access */

    int tid = threadIdx.x;
    int a = blockIdx.x * NTHREADS + tid;

    if (tid < NB) {
        const float* bp = boxes + tid * DOF;
        sbx[tid] = bp[0]; sby[tid] = bp[1];
        sbw[tid] = bp[3]; sbl[tid] = bp[4];
        sbyaw[tid] = bp[6];
        scls[tid] = cls[tid];
    }
    if (blockIdx.x == 0 && tid < NB) highest[tid] = 0.0f;
    __syncthreads();

    cg::grid_group grid = cg::this_grid();
    grid.sync();  /* highest zeroed before any atomicMax */

    /* anchor BEV: x,y,yaw identical across classes (grid construction); w,l per class */
    float ax   = anchors[(size_t)a * DOF + 0];
    float ay   = anchors[(size_t)a * DOF + 1];
    float ayaw = anchors[(size_t)a * DOF + 6];
    float aw0 = anchors[((size_t)(0 * NANCH) + a) * DOF + 3];
    float al0 = anchors[((size_t)(0 * NANCH) + a) * DOF + 4];
    float aw1 = anchors[((size_t)(1 * NANCH) + a) * DOF + 3];
    float al1 = anchors[((size_t)(1 * NANCH) + a) * DOF + 4];
    float aw2 = anchors[((size_t)(2 * NANCH) + a) * DOF + 3];
    float al2 = anchors[((size_t)(2 * NANCH) + a) * DOF + 4];

    float best0 = -1.0f, best1 = -1.0f, best2 = -1.0f;
    int arg0 = 0, arg1 = 0, arg2 = 0;

#pragma unroll 1
    for (int b = 0; b < NB; b++) {
        int c = scls[b];
        BBev bb; bb.x = sbx[b]; bb.y = sby[b]; bb.w = sbw[b]; bb.l = sbl[b]; bb.yaw = sbyaw[b];
        BBev ab; ab.x = ax; ab.y = ay;
        ab.w = (c == 0) ? aw0 : ((c == 1) ? aw1 : aw2);
        ab.l = (c == 0) ? al0 : ((c == 1) ? al1 : al2);
        ab.yaw = ayaw;
        float v = pair_iou(bb, ab);
        siou[tid][b] = v;
        if (v > 0.0f) atomicMax((int*)(highest + b), __float_as_int(v));
        /* per-class running max/argmax; strict > = first-index argmax.
           init -1.0 matches reference's invalid fill: valid v>=0 always wins. */
        if (c == 0)      { if (v > best0) { best0 = v; arg0 = b; } }
        else if (c == 1) { if (v > best1) { best1 = v; arg1 = b; } }
        else             { if (v > best2) { best2 = v; arg2 = b; } }
    }

    grid.sync();  /* highest complete */

    if (tid < NB) shigh[tid] = highest[tid];
    __syncthreads();

    int lab[NCLS];
#pragma unroll
    for (int c = 0; c < NCLS; c++) {
        float mv   = (c == 0) ? best0 : ((c == 1) ? best1 : best2);
        float low  = (c == 0) ? 0.45f : 0.35f;
        float high = (c == 0) ? 0.60f : 0.50f;
        int L = (mv >= high) ? 1 : ((mv >= low) ? -1 : 0);
        if (L != 1) {  /* low-quality promotion: bitwise equality vs stored value */
            for (int b = 0; b < NB; b++) {
                if (scls[b] == c) {
                    float h = shigh[b];
                    if (h > 0.0f && siou[tid][b] == h) { L = 1; break; }
                }
            }
        }
        lab[c] = L;
    }

    /* ambiguous: >1 positives across classes -> all -1 */
    int pos = 0;
#pragma unroll
    for (int c = 0; c < NCLS; c++) pos += (lab[c] == 1);
    if (pos > 1) {
#pragma unroll
        for (int c = 0; c < NCLS; c++) lab[c] = -1;
    }

    /* negative & ~positive -> all 0 (on post-ambiguity labels) */
    bool neg = false; pos = 0;
#pragma unroll
    for (int c = 0; c < NCLS; c++) { neg |= (lab[c] == 0); pos += (lab[c] == 1); }
    if (neg && pos != 1) {
#pragma unroll
        for (int c = 0; c < NCLS; c++) lab[c] = 0;
    }

    /* loss mask before -1 -> 0 squash */
    bool lm = false;
#pragma unroll
    for (int c = 0; c < NCLS; c++) lm |= (lab[c] != -1);

    float* G_cls = out + OFF_GCLS;
    float* G_reg = out + OFF_GREG;
    float* M_cls = out + OFF_MCLS;
    float* M_reg = out + OFF_MREG;

    M_cls[a] = lm ? 1.0f : 0.0f;

#pragma unroll
    for (int c = 0; c < NCLS; c++) {
        int L = (lab[c] == -1) ? 0 : lab[c];
        G_cls[c * NANCH + a] = (float)L;
        if (a < NYG * NXG) M_reg[c * (NYG * NXG) + a] = (float)L;  /* yaw==0 slice */

        float v0 = 0.f, v1 = 0.f, v2 = 0.f, v3 = 0.f, v4 = 0.f, v5 = 0.f, v6 = 0.f;
        if (L == 1) {
            int am = (c == 0) ? arg0 : ((c == 1) ? arg1 : arg2);
            const float* A = anchors + ((size_t)(c * NANCH + a)) * DOF;
            const float* G = boxes + (size_t)am * DOF;
            float nrm = sqrtf(A[3] * A[3] + A[4] * A[4]);
            v0 = (G[0] - A[0]) / nrm;
            v1 = (G[1] - A[1]) / nrm;
            v2 = (G[2] - A[2]) / A[5];
            v3 = logf(G[3] / A[3]);
            v4 = logf(G[4] / A[4]);
            v5 = logf(G[5] / A[5]);
            v6 = G[6] - A[6];
        }
        size_t rb = ((size_t)(c * NANCH + a)) * DOF;
        G_reg[rb + 0] = v0; G_reg[rb + 1] = v1; G_reg[rb + 2] = v2;
        G_reg[rb + 3] = v3; G_reg[rb + 4] = v4; G_reg[rb + 5] = v5;
        G_reg[rb + 6] = v6;
    }
}

extern "C" void kernel_launch(void* const* d_in, const int* in_sizes, int n_in,
                              void* d_out, int out_size, void* d_ws, size_t ws_size,
                              hipStream_t stream) {
    const float* boxes   = (const float*)d_in[0];
    const float* anchors = (const float*)d_in[1];
    const int*   cls     = (const int*)d_in[2];
    float* out = (float*)d_out;
    float* highest = (float*)d_ws;  /* 32 floats, zeroed in-kernel each call */

    void* args[] = { (void*)&boxes, (void*)&anchors, (void*)&cls,
                     (void*)&out, (void*)&highest };
    hipLaunchCooperativeKernel((void*)fused_kernel, dim3(NBLOCKS), dim3(NTHREADS),
                               args, 0, stream);
}

// Round 3
// 44.260 us; speedup vs baseline: 1.9895x; 1.9895x over previous
//
#include <hip/hip_runtime.h>
#include <math.h>

#define NCLS 3
#define NYAW 2
#define NYG 160
#define NXG 160
#define NB 32
#define NANCH (NYAW * NYG * NXG)   /* 51200 */
#define DOF 7
#define EPSI 1e-8f

/* output layout (floats) */
#define OFF_GCLS 0
#define OFF_GREG (NCLS * NANCH)                    /* 153600 */
#define OFF_MCLS (OFF_GREG + NCLS * NANCH * DOF)   /* 1228800 */
#define OFF_MREG (OFF_MCLS + NANCH)                /* 1280000 */

struct BBev { float x, y, w, l, yaw; };

__device__ __forceinline__ float crossv(float ax, float ay, float bx, float by) {
    return ax * by - ay * bx;
}

/* Rotated-box IoU, mirroring the reference _pair_iou step by step.
   b1 = ground-truth box (corners first in the point list), b2 = anchor. */
__device__ float pair_iou(const BBev b1, const BBev b2) {
    /* quick reject: if bounding circles don't overlap, every mask in the
       reference is false -> inter = 0 -> iou = exactly 0.0 */
    float ddx = b1.x - b2.x, ddy = b1.y - b2.y;
    float r1 = 0.5f * sqrtf(b1.w * b1.w + b1.l * b1.l);
    float r2 = 0.5f * sqrtf(b2.w * b2.w + b2.l * b2.l);
    float rr = r1 + r2 + 1e-3f;  /* margin covers the 1e-5 inside tolerance */
    if (ddx * ddx + ddy * ddy > rr * rr) return 0.0f;

    float cs1 = cosf(b1.yaw), sn1 = sinf(b1.yaw);
    float cs2 = cosf(b2.yaw), sn2 = sinf(b2.yaw);

    float c1x[4], c1y[4], c2x[4], c2y[4];
    {
        float ux = cs1 * (b1.w * 0.5f), uy = sn1 * (b1.w * 0.5f);
        float vx = -sn1 * (b1.l * 0.5f), vy = cs1 * (b1.l * 0.5f);
        c1x[0] = b1.x + ux + vx; c1y[0] = b1.y + uy + vy;
        c1x[1] = b1.x + ux - vx; c1y[1] = b1.y + uy - vy;
        c1x[2] = b1.x - ux - vx; c1y[2] = b1.y - uy - vy;
        c1x[3] = b1.x - ux + vx; c1y[3] = b1.y - uy + vy;
    }
    {
        float ux = cs2 * (b2.w * 0.5f), uy = sn2 * (b2.w * 0.5f);
        float vx = -sn2 * (b2.l * 0.5f), vy = cs2 * (b2.l * 0.5f);
        c2x[0] = b2.x + ux + vx; c2y[0] = b2.y + uy + vy;
        c2x[1] = b2.x + ux - vx; c2y[1] = b2.y + uy - vy;
        c2x[2] = b2.x - ux - vx; c2y[2] = b2.y - uy - vy;
        c2x[3] = b2.x - ux + vx; c2y[3] = b2.y - uy + vy;
    }

    /* collect valid points in reference concat order: c1, c2, ipts(i-major) */
    float qx[24], qy[24];
    int n = 0;

    for (int i = 0; i < 4; i++) {  /* c1 corners inside b2 */
        float rx = c1x[i] - b2.x, ry = c1y[i] - b2.y;
        float du = rx * cs2 + ry * sn2;
        float dv = -rx * sn2 + ry * cs2;
        if (fabsf(du) <= b2.w * 0.5f + 1e-5f && fabsf(dv) <= b2.l * 0.5f + 1e-5f) {
            qx[n] = c1x[i]; qy[n] = c1y[i]; n++;
        }
    }
    for (int i = 0; i < 4; i++) {  /* c2 corners inside b1 */
        float rx = c2x[i] - b1.x, ry = c2y[i] - b1.y;
        float du = rx * cs1 + ry * sn1;
        float dv = -rx * sn1 + ry * cs1;
        if (fabsf(du) <= b1.w * 0.5f + 1e-5f && fabsf(dv) <= b1.l * 0.5f + 1e-5f) {
            qx[n] = c2x[i]; qy[n] = c2y[i]; n++;
        }
    }
    for (int i = 0; i < 4; i++) {  /* edge-edge intersections */
        float d1x = c1x[(i + 1) & 3] - c1x[i];
        float d1y = c1y[(i + 1) & 3] - c1y[i];
        for (int j = 0; j < 4; j++) {
            float d2x = c2x[(j + 1) & 3] - c2x[j];
            float d2y = c2y[(j + 1) & 3] - c2y[j];
            float den = crossv(d1x, d1y, d2x, d2y);
            if (fabsf(den) < EPSI) continue;
            float qpx = c2x[j] - c1x[i], qpy = c2y[j] - c1y[i];
            float t = crossv(qpx, qpy, d2x, d2y) / den;
            float s = crossv(qpx, qpy, d1x, d1y) / den;
            if (t >= 0.0f && t <= 1.0f && s >= 0.0f && s <= 1.0f) {
                qx[n] = c1x[i] + t * d1x;
                qy[n] = c1y[i] + t * d1y;
                n++;
            }
        }
    }

    float inter = 0.0f;
    if (n > 0) {
        float sx = 0.0f, sy = 0.0f;
        for (int k = 0; k < n; k++) { sx += qx[k]; sy += qy[k]; }
        float cx = sx / (float)n, cy = sy / (float)n;

        float ang[24];
        for (int k = 0; k < n; k++) ang[k] = atan2f(qy[k] - cy, qx[k] - cx);

        /* stable insertion sort by angle (matches stable argsort) */
        for (int k = 1; k < n; k++) {
            float aa = ang[k], x = qx[k], y = qy[k];
            int m = k - 1;
            while (m >= 0 && ang[m] > aa) {
                ang[m + 1] = ang[m]; qx[m + 1] = qx[m]; qy[m + 1] = qy[m];
                m--;
            }
            ang[m + 1] = aa; qx[m + 1] = x; qy[m + 1] = y;
        }

        float area = 0.0f;
        for (int k = 0; k < n; k++) {
            int kn = (k + 1 == n) ? 0 : k + 1;
            area += qx[k] * qy[kn] - qx[kn] * qy[k];
        }
        inter = 0.5f * fabsf(area);
    }

    float uni = b1.w * b1.l + b2.w * b2.l - inter;
    float iou = inter / fmaxf(uni, EPSI);
    return fminf(fmaxf(iou, 0.0f), 1.0f);
}

/* one thread per (box, anchor) pair: maximal parallelism on the IoU phase.
   grid = (NANCH/256, NB); box index = blockIdx.y (uniform per block). */
__global__ void __launch_bounds__(256)
pair_kernel(const float* __restrict__ boxes,
            const float* __restrict__ anchors,
            const int* __restrict__ cls,
            float* __restrict__ iou_mat,
            float* __restrict__ highest) {
    int b = blockIdx.y;
    int a = blockIdx.x * 256 + threadIdx.x;
    int c = cls[b];  /* uniform -> scalar load */

    const float* bp = boxes + b * DOF;
    BBev bb; bb.x = bp[0]; bb.y = bp[1]; bb.w = bp[3]; bb.l = bp[4]; bb.yaw = bp[6];

    const float* ap = anchors + ((size_t)(c * NANCH) + a) * DOF;
    BBev ab; ab.x = ap[0]; ab.y = ap[1]; ab.w = ap[3]; ab.l = ap[4]; ab.yaw = ap[6];

    float v = pair_iou(bb, ab);
    iou_mat[(size_t)b * NANCH + a] = v;
    if (v > 0.0f) {
        /* float-as-int atomicMax valid for non-negative floats */
        atomicMax((int*)(highest + b), __float_as_int(v));
    }
}

/* one thread per anchor: max/argmax per class, thresholds, low-quality
   promotion (bitwise equality vs STORED matrix values), cross-class logic,
   and all four outputs. */
__global__ void __launch_bounds__(256)
assign_kernel(const float* __restrict__ boxes,
              const float* __restrict__ anchors,
              const int* __restrict__ cls,
              const float* __restrict__ iou_mat,
              const float* __restrict__ highest,
              float* __restrict__ out) {
    __shared__ int scls[NB];
    __shared__ float shigh[NB];
    __shared__ float siou[256][NB + 1];  /* +1 pad: conflict-free runtime-b access */

    int tid = threadIdx.x;
    int a = blockIdx.x * 256 + tid;

    if (tid < NB) {
        scls[tid] = cls[tid];
        shigh[tid] = highest[tid];
    }
    __syncthreads();

    float best0 = -1.0f, best1 = -1.0f, best2 = -1.0f;
    int arg0 = 0, arg1 = 0, arg2 = 0;

    for (int b = 0; b < NB; b++) {
        float v = iou_mat[(size_t)b * NANCH + a];  /* coalesced */
        siou[tid][b] = v;
        int c = scls[b];  /* uniform per b */
        /* reference row for invalid class is -1.0; valid v>=0 always beats -1.
           strict > = first-index argmax (np argmax semantics). */
        if (c == 0)      { if (v > best0) { best0 = v; arg0 = b; } }
        else if (c == 1) { if (v > best1) { best1 = v; arg1 = b; } }
        else             { if (v > best2) { best2 = v; arg2 = b; } }
    }

    int lab[NCLS];
#pragma unroll
    for (int c = 0; c < NCLS; c++) {
        float mv   = (c == 0) ? best0 : ((c == 1) ? best1 : best2);
        float low  = (c == 0) ? 0.45f : 0.35f;
        float high = (c == 0) ? 0.60f : 0.50f;
        int L = (mv >= high) ? 1 : ((mv >= low) ? -1 : 0);
        if (L != 1) {  /* low-quality promotion: bitwise equality vs stored value */
            for (int b = 0; b < NB; b++) {
                if (scls[b] == c) {
                    float h = shigh[b];
                    if (h > 0.0f && siou[tid][b] == h) { L = 1; break; }
                }
            }
        }
        lab[c] = L;
    }

    /* ambiguous: >1 positives across classes -> all -1 */
    int pos = 0;
#pragma unroll
    for (int c = 0; c < NCLS; c++) pos += (lab[c] == 1);
    if (pos > 1) {
#pragma unroll
        for (int c = 0; c < NCLS; c++) lab[c] = -1;
    }

    /* negative & ~positive -> all 0 (on post-ambiguity labels) */
    bool neg = false; pos = 0;
#pragma unroll
    for (int c = 0; c < NCLS; c++) { neg |= (lab[c] == 0); pos += (lab[c] == 1); }
    if (neg && pos != 1) {
#pragma unroll
        for (int c = 0; c < NCLS; c++) lab[c] = 0;
    }

    /* loss mask before -1 -> 0 squash */
    bool lm = false;
#pragma unroll
    for (int c = 0; c < NCLS; c++) lm |= (lab[c] != -1);

    float* G_cls = out + OFF_GCLS;
    float* G_reg = out + OFF_GREG;
    float* M_cls = out + OFF_MCLS;
    float* M_reg = out + OFF_MREG;

    M_cls[a] = lm ? 1.0f : 0.0f;

#pragma unroll
    for (int c = 0; c < NCLS; c++) {
        int L = (lab[c] == -1) ? 0 : lab[c];
        G_cls[c * NANCH + a] = (float)L;
        if (a < NYG * NXG) M_reg[c * (NYG * NXG) + a] = (float)L;  /* yaw==0 slice */

        float v0 = 0.f, v1 = 0.f, v2 = 0.f, v3 = 0.f, v4 = 0.f, v5 = 0.f, v6 = 0.f;
        if (L == 1) {
            int am = (c == 0) ? arg0 : ((c == 1) ? arg1 : arg2);
            const float* A = anchors + ((size_t)(c * NANCH + a)) * DOF;
            const float* G = boxes + (size_t)am * DOF;
            float nrm = sqrtf(A[3] * A[3] + A[4] * A[4]);
            v0 = (G[0] - A[0]) / nrm;
            v1 = (G[1] - A[1]) / nrm;
            v2 = (G[2] - A[2]) / A[5];
            v3 = logf(G[3] / A[3]);
            v4 = logf(G[4] / A[4]);
            v5 = logf(G[5] / A[5]);
            v6 = G[6] - A[6];
        }
        size_t rb = ((size_t)(c * NANCH + a)) * DOF;
        G_reg[rb + 0] = v0; G_reg[rb + 1] = v1; G_reg[rb + 2] = v2;
        G_reg[rb + 3] = v3; G_reg[rb + 4] = v4; G_reg[rb + 5] = v5;
        G_reg[rb + 6] = v6;
    }
}

extern "C" void kernel_launch(void* const* d_in, const int* in_sizes, int n_in,
                              void* d_out, int out_size, void* d_ws, size_t ws_size,
                              hipStream_t stream) {
    const float* boxes   = (const float*)d_in[0];
    const float* anchors = (const float*)d_in[1];
    const int*   cls     = (const int*)d_in[2];
    float* out = (float*)d_out;

    char* ws = (char*)d_ws;
    /* ws layout (bytes):
       [0, 6553600)         iou matrix f32 [32][51200]
       [6553600, 6553728)   highest f32 [32]                 */
    float* iou_mat = (float*)(ws);
    float* highest = (float*)(ws + 6553600);

    hipMemsetAsync(highest, 0, NB * sizeof(float), stream);

    pair_kernel<<<dim3(NANCH / 256, NB), dim3(256), 0, stream>>>(
        boxes, anchors, cls, iou_mat, highest);
    assign_kernel<<<dim3(NANCH / 256), dim3(256), 0, stream>>>(
        boxes, anchors, cls, iou_mat, highest, out);
}

// Round 4
// 43.790 us; speedup vs baseline: 2.0108x; 1.0107x over previous
//
#include <hip/hip_runtime.h>
#include <math.h>

#define NCLS 3
#define NYAW 2
#define NYG 160
#define NXG 160
#define NB 32
#define NANCH (NYAW * NYG * NXG)   /* 51200 */
#define NBLK (NANCH / 256)         /* 200 blocks per box */
#define DOF 7
#define EPSI 1e-8f

/* output layout (floats) */
#define OFF_GCLS 0
#define OFF_GREG (NCLS * NANCH)                    /* 153600 */
#define OFF_MCLS (OFF_GREG + NCLS * NANCH * DOF)   /* 1228800 */
#define OFF_MREG (OFF_MCLS + NANCH)                /* 1280000 */

struct BBev { float x, y, w, l, yaw; };

__device__ __forceinline__ float crossv(float ax, float ay, float bx, float by) {
    return ax * by - ay * bx;
}

/* Rotated-box IoU, mirroring the reference _pair_iou step by step.
   b1 = ground-truth box (corners first in the point list), b2 = anchor. */
__device__ float pair_iou(const BBev b1, const BBev b2) {
    /* quick reject: if bounding circles don't overlap, every mask in the
       reference is false -> inter = 0 -> iou = exactly 0.0 */
    float ddx = b1.x - b2.x, ddy = b1.y - b2.y;
    float r1 = 0.5f * sqrtf(b1.w * b1.w + b1.l * b1.l);
    float r2 = 0.5f * sqrtf(b2.w * b2.w + b2.l * b2.l);
    float rr = r1 + r2 + 1e-3f;  /* margin covers the 1e-5 inside tolerance */
    if (ddx * ddx + ddy * ddy > rr * rr) return 0.0f;

    float cs1 = cosf(b1.yaw), sn1 = sinf(b1.yaw);
    float cs2 = cosf(b2.yaw), sn2 = sinf(b2.yaw);

    float c1x[4], c1y[4], c2x[4], c2y[4];
    {
        float ux = cs1 * (b1.w * 0.5f), uy = sn1 * (b1.w * 0.5f);
        float vx = -sn1 * (b1.l * 0.5f), vy = cs1 * (b1.l * 0.5f);
        c1x[0] = b1.x + ux + vx; c1y[0] = b1.y + uy + vy;
        c1x[1] = b1.x + ux - vx; c1y[1] = b1.y + uy - vy;
        c1x[2] = b1.x - ux - vx; c1y[2] = b1.y - uy - vy;
        c1x[3] = b1.x - ux + vx; c1y[3] = b1.y - uy + vy;
    }
    {
        float ux = cs2 * (b2.w * 0.5f), uy = sn2 * (b2.w * 0.5f);
        float vx = -sn2 * (b2.l * 0.5f), vy = cs2 * (b2.l * 0.5f);
        c2x[0] = b2.x + ux + vx; c2y[0] = b2.y + uy + vy;
        c2x[1] = b2.x + ux - vx; c2y[1] = b2.y + uy - vy;
        c2x[2] = b2.x - ux - vx; c2y[2] = b2.y - uy - vy;
        c2x[3] = b2.x - ux + vx; c2y[3] = b2.y - uy + vy;
    }

    /* collect valid points in reference concat order: c1, c2, ipts(i-major) */
    float qx[24], qy[24];
    int n = 0;

    for (int i = 0; i < 4; i++) {  /* c1 corners inside b2 */
        float rx = c1x[i] - b2.x, ry = c1y[i] - b2.y;
        float du = rx * cs2 + ry * sn2;
        float dv = -rx * sn2 + ry * cs2;
        if (fabsf(du) <= b2.w * 0.5f + 1e-5f && fabsf(dv) <= b2.l * 0.5f + 1e-5f) {
            qx[n] = c1x[i]; qy[n] = c1y[i]; n++;
        }
    }
    for (int i = 0; i < 4; i++) {  /* c2 corners inside b1 */
        float rx = c2x[i] - b1.x, ry = c2y[i] - b1.y;
        float du = rx * cs1 + ry * sn1;
        float dv = -rx * sn1 + ry * cs1;
        if (fabsf(du) <= b1.w * 0.5f + 1e-5f && fabsf(dv) <= b1.l * 0.5f + 1e-5f) {
            qx[n] = c2x[i]; qy[n] = c2y[i]; n++;
        }
    }
    for (int i = 0; i < 4; i++) {  /* edge-edge intersections */
        float d1x = c1x[(i + 1) & 3] - c1x[i];
        float d1y = c1y[(i + 1) & 3] - c1y[i];
        for (int j = 0; j < 4; j++) {
            float d2x = c2x[(j + 1) & 3] - c2x[j];
            float d2y = c2y[(j + 1) & 3] - c2y[j];
            float den = crossv(d1x, d1y, d2x, d2y);
            if (fabsf(den) < EPSI) continue;
            float qpx = c2x[j] - c1x[i], qpy = c2y[j] - c1y[i];
            float t = crossv(qpx, qpy, d2x, d2y) / den;
            float s = crossv(qpx, qpy, d1x, d1y) / den;
            if (t >= 0.0f && t <= 1.0f && s >= 0.0f && s <= 1.0f) {
                qx[n] = c1x[i] + t * d1x;
                qy[n] = c1y[i] + t * d1y;
                n++;
            }
        }
    }

    float inter = 0.0f;
    if (n > 0) {
        float sx = 0.0f, sy = 0.0f;
        for (int k = 0; k < n; k++) { sx += qx[k]; sy += qy[k]; }
        float cx = sx / (float)n, cy = sy / (float)n;

        float ang[24];
        for (int k = 0; k < n; k++) ang[k] = atan2f(qy[k] - cy, qx[k] - cx);

        /* stable insertion sort by angle (matches stable argsort) */
        for (int k = 1; k < n; k++) {
            float aa = ang[k], x = qx[k], y = qy[k];
            int m = k - 1;
            while (m >= 0 && ang[m] > aa) {
                ang[m + 1] = ang[m]; qx[m + 1] = qx[m]; qy[m + 1] = qy[m];
                m--;
            }
            ang[m + 1] = aa; qx[m + 1] = x; qy[m + 1] = y;
        }

        float area = 0.0f;
        for (int k = 0; k < n; k++) {
            int kn = (k + 1 == n) ? 0 : k + 1;
            area += qx[k] * qy[kn] - qx[kn] * qy[k];
        }
        inter = 0.5f * fabsf(area);
    }

    float uni = b1.w * b1.l + b2.w * b2.l - inter;
    float iou = inter / fmaxf(uni, EPSI);
    return fminf(fmaxf(iou, 0.0f), 1.0f);
}

/* one thread per (box, anchor) pair. grid = (NBLK, NB).
   Writes iou matrix + per-block max (race-free, no init, no atomics). */
__global__ void __launch_bounds__(256)
pair_kernel(const float* __restrict__ boxes,
            const float* __restrict__ anchors,
            const int* __restrict__ cls,
            float* __restrict__ iou_mat,
            float* __restrict__ blockmax) {
    __shared__ float swmax[4];
    int b = blockIdx.y;
    int a = blockIdx.x * 256 + threadIdx.x;
    int c = cls[b];  /* uniform -> scalar load */

    const float* bp = boxes + b * DOF;
    BBev bb; bb.x = bp[0]; bb.y = bp[1]; bb.w = bp[3]; bb.l = bp[4]; bb.yaw = bp[6];

    const float* ap = anchors + ((size_t)(c * NANCH) + a) * DOF;
    BBev ab; ab.x = ap[0]; ab.y = ap[1]; ab.w = ap[3]; ab.l = ap[4]; ab.yaw = ap[6];

    float v = pair_iou(bb, ab);
    iou_mat[(size_t)b * NANCH + a] = v;

    /* block max: wave shuffle reduce (64 lanes), then 4 partials via LDS.
       fmaxf returns one of its inputs bitwise -> exact-equality promotion OK. */
    float m = v;
    for (int off = 32; off >= 1; off >>= 1)
        m = fmaxf(m, __shfl_down(m, off, 64));
    int lane = threadIdx.x & 63;
    int wv = threadIdx.x >> 6;
    if (lane == 0) swmax[wv] = m;
    __syncthreads();
    if (threadIdx.x == 0) {
        m = fmaxf(fmaxf(swmax[0], swmax[1]), fmaxf(swmax[2], swmax[3]));
        blockmax[b * NBLK + blockIdx.x] = m;
    }
}

/* one thread per anchor: reduce blockmax -> per-box highest, then per-class
   max/argmax, thresholds, low-quality promotion (bitwise equality vs STORED
   matrix values), cross-class logic, and all four outputs. */
__global__ void __launch_bounds__(256)
assign_kernel(const float* __restrict__ boxes,
              const float* __restrict__ anchors,
              const int* __restrict__ cls,
              const float* __restrict__ iou_mat,
              const float* __restrict__ blockmax,
              float* __restrict__ out) {
    __shared__ int scls[NB];
    __shared__ float shigh[NB];
    __shared__ float siou[256][NB + 1];  /* +1 pad: conflict-free runtime-b access */

    int tid = threadIdx.x;
    int a = blockIdx.x * 256 + tid;

    if (tid < NB) scls[tid] = cls[tid];

    /* highest[b] = max over 200 block maxima. thread t -> (b = t>>3, j = t&7);
       each j strides 8 over the 200 entries, then 8-lane shfl_xor reduce. */
    {
        int b = tid >> 3, j = tid & 7;
        float m = blockmax[b * NBLK + j];
        for (int k = j + 8; k < NBLK; k += 8)
            m = fmaxf(m, blockmax[b * NBLK + k]);
        m = fmaxf(m, __shfl_xor(m, 1, 64));
        m = fmaxf(m, __shfl_xor(m, 2, 64));
        m = fmaxf(m, __shfl_xor(m, 4, 64));
        if (j == 0) shigh[b] = m;
    }
    __syncthreads();

    float best0 = -1.0f, best1 = -1.0f, best2 = -1.0f;
    int arg0 = 0, arg1 = 0, arg2 = 0;

    for (int b = 0; b < NB; b++) {
        float v = iou_mat[(size_t)b * NANCH + a];  /* coalesced */
        siou[tid][b] = v;
        int c = scls[b];  /* uniform per b */
        /* reference row for invalid class is -1.0; valid v>=0 always beats -1.
           strict > = first-index argmax (np argmax semantics). */
        if (c == 0)      { if (v > best0) { best0 = v; arg0 = b; } }
        else if (c == 1) { if (v > best1) { best1 = v; arg1 = b; } }
        else             { if (v > best2) { best2 = v; arg2 = b; } }
    }

    int lab[NCLS];
#pragma unroll
    for (int c = 0; c < NCLS; c++) {
        float mv   = (c == 0) ? best0 : ((c == 1) ? best1 : best2);
        float low  = (c == 0) ? 0.45f : 0.35f;
        float high = (c == 0) ? 0.60f : 0.50f;
        int L = (mv >= high) ? 1 : ((mv >= low) ? -1 : 0);
        if (L != 1) {  /* low-quality promotion: bitwise equality vs stored value */
            for (int b = 0; b < NB; b++) {
                if (scls[b] == c) {
                    float h = shigh[b];
                    if (h > 0.0f && siou[tid][b] == h) { L = 1; break; }
                }
            }
        }
        lab[c] = L;
    }

    /* ambiguous: >1 positives across classes -> all -1 */
    int pos = 0;
#pragma unroll
    for (int c = 0; c < NCLS; c++) pos += (lab[c] == 1);
    if (pos > 1) {
#pragma unroll
        for (int c = 0; c < NCLS; c++) lab[c] = -1;
    }

    /* negative & ~positive -> all 0 (on post-ambiguity labels) */
    bool neg = false; pos = 0;
#pragma unroll
    for (int c = 0; c < NCLS; c++) { neg |= (lab[c] == 0); pos += (lab[c] == 1); }
    if (neg && pos != 1) {
#pragma unroll
        for (int c = 0; c < NCLS; c++) lab[c] = 0;
    }

    /* loss mask before -1 -> 0 squash */
    bool lm = false;
#pragma unroll
    for (int c = 0; c < NCLS; c++) lm |= (lab[c] != -1);

    float* G_cls = out + OFF_GCLS;
    float* G_reg = out + OFF_GREG;
    float* M_cls = out + OFF_MCLS;
    float* M_reg = out + OFF_MREG;

    M_cls[a] = lm ? 1.0f : 0.0f;

#pragma unroll
    for (int c = 0; c < NCLS; c++) {
        int L = (lab[c] == -1) ? 0 : lab[c];
        G_cls[c * NANCH + a] = (float)L;
        if (a < NYG * NXG) M_reg[c * (NYG * NXG) + a] = (float)L;  /* yaw==0 slice */

        float v0 = 0.f, v1 = 0.f, v2 = 0.f, v3 = 0.f, v4 = 0.f, v5 = 0.f, v6 = 0.f;
        if (L == 1) {
            int am = (c == 0) ? arg0 : ((c == 1) ? arg1 : arg2);
            const float* A = anchors + ((size_t)(c * NANCH + a)) * DOF;
            const float* G = boxes + (size_t)am * DOF;
            float nrm = sqrtf(A[3] * A[3] + A[4] * A[4]);
            v0 = (G[0] - A[0]) / nrm;
            v1 = (G[1] - A[1]) / nrm;
            v2 = (G[2] - A[2]) / A[5];
            v3 = logf(G[3] / A[3]);
            v4 = logf(G[4] / A[4]);
            v5 = logf(G[5] / A[5]);
            v6 = G[6] - A[6];
        }
        size_t rb = ((size_t)(c * NANCH + a)) * DOF;
        G_reg[rb + 0] = v0; G_reg[rb + 1] = v1; G_reg[rb + 2] = v2;
        G_reg[rb + 3] = v3; G_reg[rb + 4] = v4; G_reg[rb + 5] = v5;
        G_reg[rb + 6] = v6;
    }
}

extern "C" void kernel_launch(void* const* d_in, const int* in_sizes, int n_in,
                              void* d_out, int out_size, void* d_ws, size_t ws_size,
                              hipStream_t stream) {
    const float* boxes   = (const float*)d_in[0];
    const float* anchors = (const float*)d_in[1];
    const int*   cls     = (const int*)d_in[2];
    float* out = (float*)d_out;

    char* ws = (char*)d_ws;
    /* ws layout (bytes):
       [0, 6553600)         iou matrix f32 [32][51200]
       [6553600, 6579200)   blockmax f32 [32][200]  (every slot written
                            unconditionally each call -> no init needed) */
    float* iou_mat  = (float*)(ws);
    float* blockmax = (float*)(ws + 6553600);

    pair_kernel<<<dim3(NBLK, NB), dim3(256), 0, stream>>>(
        boxes, anchors, cls, iou_mat, blockmax);
    assign_kernel<<<dim3(NBLK), dim3(256), 0, stream>>>(
        boxes, anchors, cls, iou_mat, blockmax, out);
}